// Round 8
// baseline (161.454 us; speedup 1.0000x reference)
//
#include <hip/hip_runtime.h>

#define NSUB 48      // pupil nonzero rows/cols are [8,56) of the 64x64 grid
#define J0   8
#define PIF  3.14159265358979323846f
#define C8   0.70710678118654752440f   // sqrt(2)/2

// radix-4 butterfly: A_q = sum_s i^{s*q} B_s   (16 real adds)
#define R4BFLY(B0r,B0i,B1r,B1i,B2r,B2i,B3r,B3i, A0r,A0i,A1r,A1i,A2r,A2i,A3r,A3i) \
  { float c0r=(B0r)+(B2r), c0i=(B0i)+(B2i), d0r=(B0r)-(B2r), d0i=(B0i)-(B2i);     \
    float c1r=(B1r)+(B3r), c1i=(B1i)+(B3i), d1r=(B1r)-(B3r), d1i=(B1i)-(B3i);     \
    A0r=c0r+c1r; A0i=c0i+c1i; A2r=c0r-c1r; A2i=c0i-c1i;                           \
    A1r=d0r-d1i; A1i=d0i+d1r; A3r=d0r+d1i; A3i=d0i-d1r; }

// One pupil element: P[k,j] = mag * e^{i*(pupil_phase + prop*z - (2pi/256)((j-32)x+(k-32)y))}
__device__ __forceinline__ float2 pupil_elem(int kk, int jj, float x, float y, float z,
                                             const float* __restrict__ phase_in)
{
    const float c1 = PIF / 128.0f;  // 2*pi/256
    const int j = jj + J0, k = kk + J0;
    const float us = ((float)(2 * j) * (1.0f / 63.0f) - 1.0f) * (4.0f / 3.0f);
    const float vs = ((float)(2 * k) * (1.0f / 63.0f) - 1.0f) * (4.0f / 3.0f);
    const float r2 = us * us + vs * vs;
    float re = 0.0f, im = 0.0f;
    if (r2 <= 1.0f) {
        const float prop = sqrtf(fmaxf(1.0f - r2, 0.0f));
        const float ph = phase_in[j * 64 + k] + prop * z
                         - c1 * ((float)(j - 32) * x + (float)(k - 32) * y);
        float s, c;
        __sincosf(ph, &s, &c);
        re = c; im = s;
    }
    return make_float2(re, im);
}

// Fused kernel: block = (pair, rres 0..3, h 0..1). Compute body identical to the
// round-7-validated psf_max (band v,u in [-96,96), radix-8 F, k-mod-4 G class
// sums, mask skip). NEW: single-dispatch fast path — all 2048 blocks increment
// a per-batch counter (32 producers per b); the last arriver combines batch b's
// output. Device-scope fences around the atomic handle XCD non-coherence (G16).
__global__ __launch_bounds__(192, 4)
void psf_fused_kernel(const float* __restrict__ X, const float* __restrict__ Y,
                      const float* __restrict__ Z, const float* __restrict__ Pmask,
                      const float* __restrict__ phase_in,
                      const float* __restrict__ Aamp, const float* __restrict__ BG,
                      float* __restrict__ maxws8, unsigned* __restrict__ ctr,
                      float* __restrict__ stash, float* __restrict__ out,
                      int do_stash)
{
    const int tid  = threadIdx.x;
    const int pair = blockIdx.x >> 3;
    const int rres = (blockIdx.x >> 1) & 3;
    const int h    = blockIdx.x & 1;
    const bool active = (Pmask[pair] > 0.5f);   // block-uniform

    __shared__ float2 tw[256];
    __shared__ __align__(16) float2 PG[NSUB * NSUB]; // P: [kk*48+jj]; G: [jj*26+l]
    __shared__ float red[3];
    __shared__ float csc[4], cbgv[4];
    __shared__ int cwin;

    if (active) {
    for (int t = tid; t < 256; t += 192) {
        float s, c;
        __sincosf((float)t * (PIF / 128.0f), &s, &c);
        tw[t] = make_float2(c, s);
    }
    {
        const float x = X[pair], y = Y[pair], z = Z[pair];
        for (int idx = tid; idx < NSUB * NSUB; idx += 192) {
            const int kk = idx / NSUB, jj2 = idx - kk * NSUB;
            PG[idx] = pupil_elem(kk, jj2, x, y, z, phase_in);
        }
    }
    __syncthreads();

    // ---- G phase: 192 threads = (jj, vg 0..3). Each owns m in {h+4vg, h+4vg+2}.
    const int jj = tid % NSUB;
    const int vg = tid / NSUB;
    const int m0 = h + 4 * vg;
    float GBr[2][4], GBi[2][4];
    {
        float wrp[2] = {1.f, 1.f}, wip[2] = {0.f, 0.f};
        float srp[2], sip[2];
        _Pragma("unroll")
        for (int p = 0; p < 2; ++p) {
            const int v = rres + 4 * (m0 + 2 * p);
            const float2 st = tw[(4 * v) & 255];
            srp[p] = st.x; sip[p] = st.y;
            _Pragma("unroll")
            for (int s = 0; s < 4; ++s) { GBr[p][s] = 0.f; GBi[p][s] = 0.f; }
        }
        #pragma unroll 3
        for (int t = 0; t < 12; ++t) {
            const float2 p0 = PG[(4 * t + 0) * NSUB + jj];
            const float2 p1 = PG[(4 * t + 1) * NSUB + jj];
            const float2 p2 = PG[(4 * t + 2) * NSUB + jj];
            const float2 p3 = PG[(4 * t + 3) * NSUB + jj];
            _Pragma("unroll")
            for (int p = 0; p < 2; ++p) {
                const float wr = wrp[p], wi = wip[p];
                GBr[p][0] = fmaf(p0.x, wr, fmaf(-p0.y, wi, GBr[p][0]));
                GBi[p][0] = fmaf(p0.x, wi, fmaf( p0.y, wr, GBi[p][0]));
                GBr[p][1] = fmaf(p1.x, wr, fmaf(-p1.y, wi, GBr[p][1]));
                GBi[p][1] = fmaf(p1.x, wi, fmaf( p1.y, wr, GBi[p][1]));
                GBr[p][2] = fmaf(p2.x, wr, fmaf(-p2.y, wi, GBr[p][2]));
                GBi[p][2] = fmaf(p2.x, wi, fmaf( p2.y, wr, GBi[p][2]));
                GBr[p][3] = fmaf(p3.x, wr, fmaf(-p3.y, wi, GBr[p][3]));
                GBi[p][3] = fmaf(p3.x, wi, fmaf( p3.y, wr, GBi[p][3]));
                const float tt = wi * sip[p];
                wrp[p] = fmaf(wr, srp[p], -tt);
                wip[p] = fmaf(wr, sip[p], wi * srp[p]);
            }
        }
    }
    __syncthreads();   // all P reads done; PG becomes G storage

    _Pragma("unroll")
    for (int p = 0; p < 2; ++p) {
        const int m = m0 + 2 * p;
        const int v = rres + 4 * m;
        float Tr[4], Ti[4];
        _Pragma("unroll")
        for (int s = 0; s < 4; ++s) {
            const float2 u2 = tw[((s + 8) * v) & 255];
            Tr[s] = GBr[p][s] * u2.x - GBi[p][s] * u2.y;
            Ti[s] = GBr[p][s] * u2.y + GBi[p][s] * u2.x;
        }
        float A0r,A0i,A1r,A1i,A2r,A2i,A3r,A3i;
        R4BFLY(Tr[0],Ti[0], Tr[1],Ti[1], Tr[2],Ti[2], Tr[3],Ti[3],
               A0r,A0i, A1r,A1i, A2r,A2i, A3r,A3i);
        PG[jj * 26 + (m >> 1)]        = make_float2(A0r, A0i);
        if (m < 8)
            PG[jj * 26 + ((m + 16) >> 1)] = make_float2(A1r, A1i);
        else
            PG[jj * 26 + ((m + 16) >> 1)] = make_float2(A2r, A2i);
        PG[jj * 26 + ((m + 32) >> 1)] = make_float2(A3r, A3i);
    }
    __syncthreads();

    // ---- F phase, radix-8: 192 threads = (ub 0..31, vgrp 0..5). u = ub + 32t.
    const int ub = tid & 31;
    const int vgrp = tid >> 5;
    const float2 w0l = tw[(8 * ub) & 255];
    const float2 stl = tw[ub];
    const float crr = stl.x, cii = stl.y;
    const int l0 = vgrp * 4;

    float FBr[8][4], FBi[8][4];
    _Pragma("unroll")
    for (int s = 0; s < 8; ++s) {
        _Pragma("unroll")
        for (int vv = 0; vv < 4; ++vv) { FBr[s][vv] = 0.f; FBi[s][vv] = 0.f; }
    }
    float wr = w0l.x, wi = w0l.y;
#define FBODY(JJ, S) do {                                                         \
    const float4 g01 = *(const float4*)&PG[(JJ) * 26 + l0];                       \
    const float4 g23 = *(const float4*)&PG[(JJ) * 26 + l0 + 2];                   \
    FBr[S][0] = fmaf(g01.x, wr, fmaf(-g01.y, wi, FBr[S][0]));                     \
    FBi[S][0] = fmaf(g01.x, wi, fmaf( g01.y, wr, FBi[S][0]));                     \
    FBr[S][1] = fmaf(g01.z, wr, fmaf(-g01.w, wi, FBr[S][1]));                     \
    FBi[S][1] = fmaf(g01.z, wi, fmaf( g01.w, wr, FBi[S][1]));                     \
    FBr[S][2] = fmaf(g23.x, wr, fmaf(-g23.y, wi, FBr[S][2]));                     \
    FBi[S][2] = fmaf(g23.x, wi, fmaf( g23.y, wr, FBi[S][2]));                     \
    FBr[S][3] = fmaf(g23.z, wr, fmaf(-g23.w, wi, FBr[S][3]));                     \
    FBi[S][3] = fmaf(g23.z, wi, fmaf( g23.w, wr, FBi[S][3]));                     \
    const float tt = wi * cii;                                                    \
    const float nr = fmaf(wr, crr, -tt);                                          \
    const float ni = fmaf(wr, cii, wi * crr);                                     \
    wr = nr; wi = ni; } while (0)
    #pragma unroll 1
    for (int j8 = 0; j8 < NSUB; j8 += 8) {
        FBODY(j8 + 0, 0); FBODY(j8 + 1, 1); FBODY(j8 + 2, 2); FBODY(j8 + 3, 3);
        FBODY(j8 + 4, 4); FBODY(j8 + 5, 5); FBODY(j8 + 6, 6); FBODY(j8 + 7, 7);
    }
#undef FBODY

    float lmax = 0.0f;
    const int cropkind = (vgrp == 0) ? 1 : ((vgrp == 5) ? 2 : 0);
    _Pragma("unroll")
    for (int vv = 0; vv < 4; ++vv) {
        float E0r,E0i,E1r,E1i,E2r,E2i,E3r,E3i;
        float O0r,O0i,O1r,O1i,O2r,O2i,O3r,O3i;
        R4BFLY(FBr[0][vv],FBi[0][vv], FBr[2][vv],FBi[2][vv],
               FBr[4][vv],FBi[4][vv], FBr[6][vv],FBi[6][vv],
               E0r,E0i, E1r,E1i, E2r,E2i, E3r,E3i);
        R4BFLY(FBr[1][vv],FBi[1][vv], FBr[3][vv],FBi[3][vv],
               FBr[5][vv],FBi[5][vv], FBr[7][vv],FBi[7][vv],
               O0r,O0i, O1r,O1i, O2r,O2i, O3r,O3i);
        const float F0r = E0r + O0r, F0i = E0i + O0i;
        const float F2r = E2r - O2i, F2i = E2i + O2r;
        const float F6r = E2r + O2i, F6i = E2i - O2r;
        const float p1r = C8 * (O1r - O1i), p1i = C8 * (O1r + O1i);
        const float F1r = E1r + p1r, F1i = E1i + p1i;
        const float F5r = E1r - p1r, F5i = E1i - p1i;
        const float q3r = -C8 * (O3r + O3i), q3i = C8 * (O3r - O3i);
        const float F7r = E3r - q3r, F7i = E3i - q3i;
        const float m0 = fmaf(F0r, F0r, F0i * F0i);
        const float m1 = fmaf(F1r, F1r, F1i * F1i);
        const float m2 = fmaf(F2r, F2r, F2i * F2i);
        const float m5 = fmaf(F5r, F5r, F5i * F5i);
        const float m6 = fmaf(F6r, F6r, F6i * F6i);
        const float m7 = fmaf(F7r, F7r, F7i * F7i);
        lmax = fmaxf(lmax, fmaxf(fmaxf(m0, m1), fmaxf(m2, fmaxf(m5, fmaxf(m6, m7)))));
        if (do_stash && cropkind) {
            const int vp = (cropkind == 1) ? (h + 2 * vv) : (56 + h + 2 * vv);
            const int c = ((rres + 4 * vp) + 32) & 255;   // crop col < 64
            stash[pair * 4096 + ((ub + 32) << 6) + c] = m0;
            stash[pair * 4096 + (ub << 6) + c] = m7;
        }
    }

    for (int off = 32; off > 0; off >>= 1)
        lmax = fmaxf(lmax, __shfl_down(lmax, off, 64));
    if ((tid & 63) == 0) red[tid >> 6] = lmax;
    __syncthreads();
    if (tid == 0)
        maxws8[blockIdx.x] = fmaxf(fmaxf(red[0], red[1]), red[2]);
    }  // if (active)

    // ---- fused combine (fast path only): last of 32 producer blocks per batch b.
    if (!do_stash) return;
    const int b = pair >> 2;
    if (tid == 0) {
        __threadfence();   // release: stash/maxws8 stores visible device-wide
        const unsigned old = atomicAdd(&ctr[b], 1u);
        // ws poisoned to 0xAA before every launch -> init 0xAAAAAAAA; also accept 0-init.
        cwin = (old == 0xAAAAAAAAu + 31u || old == 31u) ? 1 : 0;
    }
    __syncthreads();
    if (!cwin) return;

    __threadfence();       // acquire: see all 32 producers' stores
    if (tid < 4) {
        const int pr = b * 4 + tid;
        float s = 0.0f, bgv = 0.0f;
        if (Pmask[pr] > 0.5f) {
            float mx = maxws8[pr * 8];
            _Pragma("unroll")
            for (int q = 1; q < 8; ++q) mx = fmaxf(mx, maxws8[pr * 8 + q]);
            s = Aamp[pr] / mx;
            bgv = BG[pr];
        }
        csc[tid] = s; cbgv[tid] = bgv;
    }
    __syncthreads();
    const float bgt = (cbgv[0] + cbgv[1]) + (cbgv[2] + cbgv[3]);
    const float s0 = csc[0], s1 = csc[1], s2 = csc[2], s3 = csc[3];
    const float* st0 = stash + (b * 4 + 0) * 4096;
    const float* st1 = stash + (b * 4 + 1) * 4096;
    const float* st2 = stash + (b * 4 + 2) * 4096;
    const float* st3 = stash + (b * 4 + 3) * 4096;
    float* outb = out + b * 4096;
    for (int i = tid; i < 1024; i += 192) {
        // masked pairs have s==0; poison * 0 == -0, safe to accumulate.
        const float4 v0 = *(const float4*)(st0 + i * 4);
        const float4 v1 = *(const float4*)(st1 + i * 4);
        const float4 v2 = *(const float4*)(st2 + i * 4);
        const float4 v3 = *(const float4*)(st3 + i * 4);
        float4 acc;
        acc.x = fmaf(v0.x, s0, fmaf(v1.x, s1, fmaf(v2.x, s2, fmaf(v3.x, s3, bgt))));
        acc.y = fmaf(v0.y, s0, fmaf(v1.y, s1, fmaf(v2.y, s2, fmaf(v3.y, s3, bgt))));
        acc.z = fmaf(v0.z, s0, fmaf(v1.z, s1, fmaf(v2.z, s2, fmaf(v3.z, s3, bgt))));
        acc.w = fmaf(v0.w, s0, fmaf(v1.w, s1, fmaf(v2.w, s2, fmaf(v3.w, s3, bgt))));
        *(float4*)(outb + i * 4) = acc;
    }
}

// Fallback crop kernel (only if ws too small for the stash): recomputes the
// cropped field values directly (validated round 2), reads 8 partial maxes.
__global__ __launch_bounds__(256, 4)
void psf_crop_kernel(const float* __restrict__ X, const float* __restrict__ Y,
                     const float* __restrict__ Z, const float* __restrict__ Aamp,
                     const float* __restrict__ BG, const float* __restrict__ Pmask,
                     const float* __restrict__ phase_in,
                     const float* __restrict__ maxws8,
                     float* __restrict__ out)
{
    const int pair = blockIdx.x >> 2;
    const int vblk = blockIdx.x & 3;
    if (Pmask[pair] <= 0.5f) return;

    __shared__ float2 tw[256];
    __shared__ __align__(16) float2 PG[NSUB * NSUB];

    const int tid = threadIdx.x;
    const float x = X[pair], y = Y[pair], z = Z[pair];
    {
        float s, c;
        __sincosf((float)tid * (PIF / 128.0f), &s, &c);
        tw[tid] = make_float2(c, s);
    }
    for (int idx = tid; idx < NSUB * NSUB; idx += 256) {
        const int kk = idx / NSUB, jj2 = idx - kk * NSUB;
        PG[idx] = pupil_elem(kk, jj2, x, y, z, phase_in);
    }
    __syncthreads();

    const int jj = tid % 48;
    const int vg = tid / 48;
    float gr4[4], gi4[4], gwr[4], gwi[4], gcr[4], gci[4];
    if (tid < 192) {
        _Pragma("unroll")
        for (int c = 0; c < 4; ++c) {
            const int acol = vblk * 16 + vg * 4 + c;
            const int v = (acol + 224) & 255;
            const float2 w0 = tw[(J0 * v) & 255];
            const float2 st = tw[v];
            gwr[c] = w0.x; gwi[c] = w0.y; gcr[c] = st.x; gci[c] = st.y;
            gr4[c] = 0.0f; gi4[c] = 0.0f;
        }
        #pragma unroll 4
        for (int kk = 0; kk < NSUB; ++kk) {
            const float2 pv = PG[kk * NSUB + jj];
            _Pragma("unroll")
            for (int c = 0; c < 4; ++c) {
                gr4[c] = fmaf(pv.x, gwr[c], fmaf(-pv.y, gwi[c], gr4[c]));
                gi4[c] = fmaf(pv.x, gwi[c], fmaf( pv.y, gwr[c], gi4[c]));
                const float t  = gwi[c] * gci[c];
                const float nr = fmaf(gwr[c], gcr[c], -t);
                const float ni = fmaf(gwr[c], gci[c], gwi[c] * gcr[c]);
                gwr[c] = nr; gwi[c] = ni;
            }
        }
    }
    __syncthreads();
    if (tid < 192) {
        _Pragma("unroll")
        for (int c = 0; c < 4; ++c)
            PG[jj * 18 + vg * 4 + c] = make_float2(gr4[c], gi4[c]);
    }
    __syncthreads();

    float mx = maxws8[pair * 8];
    _Pragma("unroll")
    for (int q = 1; q < 8; ++q) mx = fmaxf(mx, maxws8[pair * 8 + q]);
    const float scale = Aamp[pair] / mx;
    const float bgv = BG[pair];

    const int lane = tid & 63;
    const int wv = tid >> 6;
    const int u = (lane + 224) & 255;
    const float2 w0l = tw[(8 * u) & 255];
    const float2 stl = tw[u];
    const float crr = stl.x, cii = stl.y;
    const int vb = wv * 4;
    float ar[4], ai[4];
    _Pragma("unroll")
    for (int c = 0; c < 4; ++c) { ar[c] = 0.0f; ai[c] = 0.0f; }
    float wr = w0l.x, wi = w0l.y;
    #pragma unroll 4
    for (int j = 0; j < NSUB; ++j) {
        const float4 g01 = *(const float4*)&PG[j * 18 + vb];
        const float4 g23 = *(const float4*)&PG[j * 18 + vb + 2];
        ar[0] = fmaf(g01.x, wr, fmaf(-g01.y, wi, ar[0]));
        ai[0] = fmaf(g01.x, wi, fmaf( g01.y, wr, ai[0]));
        ar[1] = fmaf(g01.z, wr, fmaf(-g01.w, wi, ar[1]));
        ai[1] = fmaf(g01.z, wi, fmaf( g01.w, wr, ai[1]));
        ar[2] = fmaf(g23.x, wr, fmaf(-g23.y, wi, ar[2]));
        ai[2] = fmaf(g23.x, wi, fmaf( g23.y, wr, ai[2]));
        ar[3] = fmaf(g23.z, wr, fmaf(-g23.w, wi, ar[3]));
        ai[3] = fmaf(g23.z, wi, fmaf( g23.w, wr, ai[3]));
        const float t  = wi * cii;
        const float nr = fmaf(wr, crr, -t);
        const float ni = fmaf(wr, cii, wi * crr);
        wr = nr; wi = ni;
    }

    float* outb = out + ((pair >> 2) << 12) + lane * 64 + vblk * 16 + vb;
    _Pragma("unroll")
    for (int c = 0; c < 4; ++c) {
        const float m = fmaf(ar[c], ar[c], ai[c] * ai[c]);
        atomicAdd(&outb[c], fmaf(m, scale, bgv));
    }
}

extern "C" void kernel_launch(void* const* d_in, const int* in_sizes, int n_in,
                              void* d_out, int out_size, void* d_ws, size_t ws_size,
                              hipStream_t stream)
{
    const float* x  = (const float*)d_in[0];
    const float* y  = (const float*)d_in[1];
    const float* z  = (const float*)d_in[2];
    const float* A  = (const float*)d_in[3];
    const float* bg = (const float*)d_in[4];
    const float* p  = (const float*)d_in[5];
    const float* ph = (const float*)d_in[6];
    float* out = (float*)d_out;

    float*    maxws8 = (float*)d_ws;                 // 2048 floats (8 partials / pair)
    unsigned* ctr    = (unsigned*)(maxws8 + 2048);   // 64 batch counters (poison-init OK)
    float*    stash  = (float*)(ctr + 64);           // 256 x 4096 floats = 4 MB (16B-aligned)

    const size_t need_min = (2048u + 64u + 256u * 4096u) * sizeof(float);
    const int do_stash = (ws_size >= need_min) ? 1 : 0;

    hipLaunchKernelGGL(psf_fused_kernel, dim3(2048), dim3(192), 0, stream,
                       x, y, z, p, ph, A, bg, maxws8, ctr, stash, out, do_stash);
    if (!do_stash) {
        hipMemsetAsync(d_out, 0, (size_t)out_size * sizeof(float), stream);
        hipLaunchKernelGGL(psf_crop_kernel, dim3(1024), dim3(256), 0, stream,
                           x, y, z, A, bg, p, ph, maxws8, out);
    }
}

// Round 9
// 90.945 us; speedup vs baseline: 1.7753x; 1.7753x over previous
//
#include <hip/hip_runtime.h>

#define NSUB 48      // pupil nonzero rows/cols are [8,56) of the 64x64 grid
#define J0   8
#define PIF  3.14159265358979323846f
#define C8   0.70710678118654752440f   // sqrt(2)/2

// radix-4 butterfly: A_q = sum_s i^{s*q} B_s   (16 real adds)
#define R4BFLY(B0r,B0i,B1r,B1i,B2r,B2i,B3r,B3i, A0r,A0i,A1r,A1i,A2r,A2i,A3r,A3i) \
  { float c0r=(B0r)+(B2r), c0i=(B0i)+(B2i), d0r=(B0r)-(B2r), d0i=(B0i)-(B2i);     \
    float c1r=(B1r)+(B3r), c1i=(B1i)+(B3i), d1r=(B1r)-(B3r), d1i=(B1i)-(B3i);     \
    A0r=c0r+c1r; A0i=c0i+c1i; A2r=c0r-c1r; A2i=c0i-c1i;                           \
    A1r=d0r-d1i; A1i=d0i+d1r; A3r=d0r+d1i; A3i=d0i-d1r; }

// One pupil element: P[k,j] = mag * e^{i*(pupil_phase + prop*z - (2pi/256)((j-32)x+(k-32)y))}
__device__ __forceinline__ float2 pupil_elem(int kk, int jj, float x, float y, float z,
                                             const float* __restrict__ phase_in)
{
    const float c1 = PIF / 128.0f;  // 2*pi/256
    const int j = jj + J0, k = kk + J0;
    const float us = ((float)(2 * j) * (1.0f / 63.0f) - 1.0f) * (4.0f / 3.0f);
    const float vs = ((float)(2 * k) * (1.0f / 63.0f) - 1.0f) * (4.0f / 3.0f);
    const float r2 = us * us + vs * vs;
    float re = 0.0f, im = 0.0f;
    if (r2 <= 1.0f) {
        const float prop = sqrtf(fmaxf(1.0f - r2, 0.0f));
        const float ph = phase_in[j * 64 + k] + prop * z
                         - c1 * ((float)(j - 32) * x + (float)(k - 32) * y);
        float s, c;
        __sincosf(ph, &s, &c);
        re = c; im = s;
    }
    return make_float2(re, im);
}

// Kernel 1: block = (pair, rres 0..3, h 0..1): v = rres + 4*vloc', vloc' == h (mod 2).
// Retained vloc' set (band v in [-96,96) mod 256, which CONTAINS the crop):
//   vloc' in [0,24) u [40,64) -> slot s = vloc' if vloc'<24 else vloc'-16,
//   per-parity local slot l = s>>1 in [0,24).
// PSF peak sits near v=0 pre-ifftshift (crop maps a -> (a+224)&255); displacement
// <= tilt(~27) + defocus caustic(~8.6|z| <= ~58) << 96 (validated round 6).
// Masked pairs (p<=0.5) contribute nothing to the output -> early exit (~half).
// NOTE (round 8 post-mortem): do NOT fuse the combine via device-scope fences +
// last-arriver atomics — per-block __threadfence() L2 writeback/invalidate on
// non-coherent XCD L2s cost ~90 us. The dispatch boundary is the cheap fence.
__global__ __launch_bounds__(192, 4)
void psf_max_kernel(const float* __restrict__ X, const float* __restrict__ Y,
                    const float* __restrict__ Z, const float* __restrict__ Pmask,
                    const float* __restrict__ phase_in,
                    float* __restrict__ maxws8, float* __restrict__ stash,
                    int do_stash)
{
    const int tid  = threadIdx.x;
    const int pair = blockIdx.x >> 3;
    const int rres = (blockIdx.x >> 1) & 3;
    const int h    = blockIdx.x & 1;
    if (Pmask[pair] <= 0.5f) return;   // block-uniform; stash/max never read for masked

    __shared__ float2 tw[256];
    __shared__ __align__(16) float2 PG[NSUB * NSUB]; // P: [kk*48+jj]; G: [jj*26+l]
    __shared__ float red[3];

    for (int t = tid; t < 256; t += 192) {
        float s, c;
        __sincosf((float)t * (PIF / 128.0f), &s, &c);
        tw[t] = make_float2(c, s);
    }
    {
        const float x = X[pair], y = Y[pair], z = Z[pair];
        for (int idx = tid; idx < NSUB * NSUB; idx += 192) {
            const int kk = idx / NSUB, jj2 = idx - kk * NSUB;
            PG[idx] = pupil_elem(kk, jj2, x, y, z, phase_in);
        }
    }
    __syncthreads();

    // ---- G phase: 192 threads = (jj, vg 0..3). Each owns m in {h+4vg, h+4vg+2}.
    // Class sums over kk mod 4 with step omega^{4v}; v-quads via butterfly.
    const int jj = tid % NSUB;
    const int vg = tid / NSUB;
    const int m0 = h + 4 * vg;
    float GBr[2][4], GBi[2][4];
    {
        float wrp[2] = {1.f, 1.f}, wip[2] = {0.f, 0.f};
        float srp[2], sip[2];
        _Pragma("unroll")
        for (int p = 0; p < 2; ++p) {
            const int v = rres + 4 * (m0 + 2 * p);
            const float2 st = tw[(4 * v) & 255];
            srp[p] = st.x; sip[p] = st.y;
            _Pragma("unroll")
            for (int s = 0; s < 4; ++s) { GBr[p][s] = 0.f; GBi[p][s] = 0.f; }
        }
        #pragma unroll 3
        for (int t = 0; t < 12; ++t) {
            const float2 p0 = PG[(4 * t + 0) * NSUB + jj];
            const float2 p1 = PG[(4 * t + 1) * NSUB + jj];
            const float2 p2 = PG[(4 * t + 2) * NSUB + jj];
            const float2 p3 = PG[(4 * t + 3) * NSUB + jj];
            _Pragma("unroll")
            for (int p = 0; p < 2; ++p) {
                const float wr = wrp[p], wi = wip[p];
                GBr[p][0] = fmaf(p0.x, wr, fmaf(-p0.y, wi, GBr[p][0]));
                GBi[p][0] = fmaf(p0.x, wi, fmaf( p0.y, wr, GBi[p][0]));
                GBr[p][1] = fmaf(p1.x, wr, fmaf(-p1.y, wi, GBr[p][1]));
                GBi[p][1] = fmaf(p1.x, wi, fmaf( p1.y, wr, GBi[p][1]));
                GBr[p][2] = fmaf(p2.x, wr, fmaf(-p2.y, wi, GBr[p][2]));
                GBi[p][2] = fmaf(p2.x, wi, fmaf( p2.y, wr, GBi[p][2]));
                GBr[p][3] = fmaf(p3.x, wr, fmaf(-p3.y, wi, GBr[p][3]));
                GBi[p][3] = fmaf(p3.x, wi, fmaf( p3.y, wr, GBi[p][3]));
                const float tt = wi * sip[p];
                wrp[p] = fmaf(wr, srp[p], -tt);
                wip[p] = fmaf(wr, sip[p], wi * srp[p]);
            }
        }
    }
    __syncthreads();   // all P reads done; PG becomes G storage

    _Pragma("unroll")
    for (int p = 0; p < 2; ++p) {
        const int m = m0 + 2 * p;
        const int v = rres + 4 * m;
        float Tr[4], Ti[4];
        _Pragma("unroll")
        for (int s = 0; s < 4; ++s) {
            const float2 u2 = tw[((s + 8) * v) & 255];
            Tr[s] = GBr[p][s] * u2.x - GBi[p][s] * u2.y;
            Ti[s] = GBr[p][s] * u2.y + GBi[p][s] * u2.x;
        }
        float A0r,A0i,A1r,A1i,A2r,A2i,A3r,A3i;
        R4BFLY(Tr[0],Ti[0], Tr[1],Ti[1], Tr[2],Ti[2], Tr[3],Ti[3],
               A0r,A0i, A1r,A1i, A2r,A2i, A3r,A3i);
        // A_q = G[j, vloc'=m+16q]. Keep q=0 (vloc'=m), q=3 (vloc'=m+48), and
        // q=1 (vloc'=m+16, iff m<8) or q=2 (vloc'=m+32, iff m>=8).
        PG[jj * 26 + (m >> 1)]        = make_float2(A0r, A0i);
        if (m < 8)
            PG[jj * 26 + ((m + 16) >> 1)] = make_float2(A1r, A1i);
        else
            PG[jj * 26 + ((m + 16) >> 1)] = make_float2(A2r, A2i);
        PG[jj * 26 + ((m + 32) >> 1)] = make_float2(A3r, A3i);
    }
    __syncthreads();

    // ---- F phase, radix-8: 192 threads = (ub 0..31, vgrp 0..5). u = ub + 32t.
    const int ub = tid & 31;
    const int vgrp = tid >> 5;
    const float2 w0l = tw[(8 * ub) & 255];
    const float2 stl = tw[ub];
    const float crr = stl.x, cii = stl.y;
    const int l0 = vgrp * 4;

    float FBr[8][4], FBi[8][4];
    _Pragma("unroll")
    for (int s = 0; s < 8; ++s) {
        _Pragma("unroll")
        for (int vv = 0; vv < 4; ++vv) { FBr[s][vv] = 0.f; FBi[s][vv] = 0.f; }
    }
    float wr = w0l.x, wi = w0l.y;
#define FBODY(JJ, S) do {                                                         \
    const float4 g01 = *(const float4*)&PG[(JJ) * 26 + l0];                       \
    const float4 g23 = *(const float4*)&PG[(JJ) * 26 + l0 + 2];                   \
    FBr[S][0] = fmaf(g01.x, wr, fmaf(-g01.y, wi, FBr[S][0]));                     \
    FBi[S][0] = fmaf(g01.x, wi, fmaf( g01.y, wr, FBi[S][0]));                     \
    FBr[S][1] = fmaf(g01.z, wr, fmaf(-g01.w, wi, FBr[S][1]));                     \
    FBi[S][1] = fmaf(g01.z, wi, fmaf( g01.w, wr, FBi[S][1]));                     \
    FBr[S][2] = fmaf(g23.x, wr, fmaf(-g23.y, wi, FBr[S][2]));                     \
    FBi[S][2] = fmaf(g23.x, wi, fmaf( g23.y, wr, FBi[S][2]));                     \
    FBr[S][3] = fmaf(g23.z, wr, fmaf(-g23.w, wi, FBr[S][3]));                     \
    FBi[S][3] = fmaf(g23.z, wi, fmaf( g23.w, wr, FBi[S][3]));                     \
    const float tt = wi * cii;                                                    \
    const float nr = fmaf(wr, crr, -tt);                                          \
    const float ni = fmaf(wr, cii, wi * crr);                                     \
    wr = nr; wi = ni; } while (0)
    #pragma unroll 1
    for (int j8 = 0; j8 < NSUB; j8 += 8) {
        FBODY(j8 + 0, 0); FBODY(j8 + 1, 1); FBODY(j8 + 2, 2); FBODY(j8 + 3, 3);
        FBODY(j8 + 4, 4); FBODY(j8 + 5, 5); FBODY(j8 + 6, 6); FBODY(j8 + 7, 7);
    }
#undef FBODY

    float lmax = 0.0f;
    const int cropkind = (vgrp == 0) ? 1 : ((vgrp == 5) ? 2 : 0);
    _Pragma("unroll")
    for (int vv = 0; vv < 4; ++vv) {
        float E0r,E0i,E1r,E1i,E2r,E2i,E3r,E3i;
        float O0r,O0i,O1r,O1i,O2r,O2i,O3r,O3i;
        R4BFLY(FBr[0][vv],FBi[0][vv], FBr[2][vv],FBi[2][vv],
               FBr[4][vv],FBi[4][vv], FBr[6][vv],FBi[6][vv],
               E0r,E0i, E1r,E1i, E2r,E2i, E3r,E3i);
        R4BFLY(FBr[1][vv],FBi[1][vv], FBr[3][vv],FBi[3][vv],
               FBr[5][vv],FBi[5][vv], FBr[7][vv],FBi[7][vv],
               O0r,O0i, O1r,O1i, O2r,O2i, O3r,O3i);
        // F_t = E[t mod 4] + e^{2 pi i t/8} O[t mod 4]; skip t=3,4 (u outside +-96 band)
        const float F0r = E0r + O0r, F0i = E0i + O0i;
        const float F2r = E2r - O2i, F2i = E2i + O2r;
        const float F6r = E2r + O2i, F6i = E2i - O2r;
        const float p1r = C8 * (O1r - O1i), p1i = C8 * (O1r + O1i);
        const float F1r = E1r + p1r, F1i = E1i + p1i;
        const float F5r = E1r - p1r, F5i = E1i - p1i;
        const float q3r = -C8 * (O3r + O3i), q3i = C8 * (O3r - O3i);
        const float F7r = E3r - q3r, F7i = E3i - q3i;
        const float m0 = fmaf(F0r, F0r, F0i * F0i);
        const float m1 = fmaf(F1r, F1r, F1i * F1i);
        const float m2 = fmaf(F2r, F2r, F2i * F2i);
        const float m5 = fmaf(F5r, F5r, F5i * F5i);
        const float m6 = fmaf(F6r, F6r, F6i * F6i);
        const float m7 = fmaf(F7r, F7r, F7i * F7i);
        lmax = fmaxf(lmax, fmaxf(fmaxf(m0, m1), fmaxf(m2, fmaxf(m5, fmaxf(m6, m7)))));
        if (do_stash && cropkind) {
            // crop rows: t=0 -> a=ub+32 (m0); t=7 -> a=ub (m7)
            const int vp = (cropkind == 1) ? (h + 2 * vv) : (56 + h + 2 * vv);
            const int c = ((rres + 4 * vp) + 32) & 255;   // crop col < 64
            stash[pair * 4096 + ((ub + 32) << 6) + c] = m0;
            stash[pair * 4096 + (ub << 6) + c] = m7;
        }
    }

    for (int off = 32; off > 0; off >>= 1)
        lmax = fmaxf(lmax, __shfl_down(lmax, off, 64));
    if ((tid & 63) == 0) red[tid >> 6] = lmax;
    __syncthreads();
    if (tid == 0)
        maxws8[blockIdx.x] = fmaxf(fmaxf(red[0], red[1]), red[2]);
}

// Kernel 2 (fast path): out[b] = sum_n mask*(stash*A/max) + sum_n mask*bg.
// Writes every output element (0 if all masked) -> no out-memset needed.
__global__ __launch_bounds__(256)
void combine_kernel(const float* __restrict__ Aamp, const float* __restrict__ BG,
                    const float* __restrict__ Pmask,
                    const float* __restrict__ maxws8, const float* __restrict__ stash,
                    float* __restrict__ out)
{
    const int b = blockIdx.x >> 2;
    const int base = (blockIdx.x & 3) * 1024 + threadIdx.x * 4;
    float4 acc = make_float4(0.f, 0.f, 0.f, 0.f);
    float bgtot = 0.0f;
    #pragma unroll
    for (int n = 0; n < 4; ++n) {
        const int pair = b * 4 + n;
        if (Pmask[pair] > 0.5f) {
            const float4 ma = *(const float4*)&maxws8[pair * 8];
            const float4 mb = *(const float4*)&maxws8[pair * 8 + 4];
            const float mx = fmaxf(fmaxf(fmaxf(ma.x, ma.y), fmaxf(ma.z, ma.w)),
                                   fmaxf(fmaxf(mb.x, mb.y), fmaxf(mb.z, mb.w)));
            const float s = Aamp[pair] / mx;
            bgtot += BG[pair];
            const float4 v = *(const float4*)(stash + pair * 4096 + base);
            acc.x = fmaf(v.x, s, acc.x);
            acc.y = fmaf(v.y, s, acc.y);
            acc.z = fmaf(v.z, s, acc.z);
            acc.w = fmaf(v.w, s, acc.w);
        }
    }
    *(float4*)(out + b * 4096 + base) =
        make_float4(acc.x + bgtot, acc.y + bgtot, acc.z + bgtot, acc.w + bgtot);
}

// Fallback crop kernel (only if ws too small for the stash): recomputes the
// cropped field values directly (validated round 2), reads 8 partial maxes.
__global__ __launch_bounds__(256, 4)
void psf_crop_kernel(const float* __restrict__ X, const float* __restrict__ Y,
                     const float* __restrict__ Z, const float* __restrict__ Aamp,
                     const float* __restrict__ BG, const float* __restrict__ Pmask,
                     const float* __restrict__ phase_in,
                     const float* __restrict__ maxws8,
                     float* __restrict__ out)
{
    const int pair = blockIdx.x >> 2;
    const int vblk = blockIdx.x & 3;
    if (Pmask[pair] <= 0.5f) return;

    __shared__ float2 tw[256];
    __shared__ __align__(16) float2 PG[NSUB * NSUB];

    const int tid = threadIdx.x;
    const float x = X[pair], y = Y[pair], z = Z[pair];
    {
        float s, c;
        __sincosf((float)tid * (PIF / 128.0f), &s, &c);
        tw[tid] = make_float2(c, s);
    }
    for (int idx = tid; idx < NSUB * NSUB; idx += 256) {
        const int kk = idx / NSUB, jj2 = idx - kk * NSUB;
        PG[idx] = pupil_elem(kk, jj2, x, y, z, phase_in);
    }
    __syncthreads();

    const int jj = tid % 48;
    const int vg = tid / 48;
    float gr4[4], gi4[4], gwr[4], gwi[4], gcr[4], gci[4];
    if (tid < 192) {
        _Pragma("unroll")
        for (int c = 0; c < 4; ++c) {
            const int acol = vblk * 16 + vg * 4 + c;
            const int v = (acol + 224) & 255;
            const float2 w0 = tw[(J0 * v) & 255];
            const float2 st = tw[v];
            gwr[c] = w0.x; gwi[c] = w0.y; gcr[c] = st.x; gci[c] = st.y;
            gr4[c] = 0.0f; gi4[c] = 0.0f;
        }
        #pragma unroll 4
        for (int kk = 0; kk < NSUB; ++kk) {
            const float2 pv = PG[kk * NSUB + jj];
            _Pragma("unroll")
            for (int c = 0; c < 4; ++c) {
                gr4[c] = fmaf(pv.x, gwr[c], fmaf(-pv.y, gwi[c], gr4[c]));
                gi4[c] = fmaf(pv.x, gwi[c], fmaf( pv.y, gwr[c], gi4[c]));
                const float t  = gwi[c] * gci[c];
                const float nr = fmaf(gwr[c], gcr[c], -t);
                const float ni = fmaf(gwr[c], gci[c], gwi[c] * gcr[c]);
                gwr[c] = nr; gwi[c] = ni;
            }
        }
    }
    __syncthreads();
    if (tid < 192) {
        _Pragma("unroll")
        for (int c = 0; c < 4; ++c)
            PG[jj * 18 + vg * 4 + c] = make_float2(gr4[c], gi4[c]);
    }
    __syncthreads();

    float mx = maxws8[pair * 8];
    _Pragma("unroll")
    for (int q = 1; q < 8; ++q) mx = fmaxf(mx, maxws8[pair * 8 + q]);
    const float scale = Aamp[pair] / mx;
    const float bgv = BG[pair];

    const int lane = tid & 63;
    const int wv = tid >> 6;
    const int u = (lane + 224) & 255;
    const float2 w0l = tw[(8 * u) & 255];
    const float2 stl = tw[u];
    const float crr = stl.x, cii = stl.y;
    const int vb = wv * 4;
    float ar[4], ai[4];
    _Pragma("unroll")
    for (int c = 0; c < 4; ++c) { ar[c] = 0.0f; ai[c] = 0.0f; }
    float wr = w0l.x, wi = w0l.y;
    #pragma unroll 4
    for (int j = 0; j < NSUB; ++j) {
        const float4 g01 = *(const float4*)&PG[j * 18 + vb];
        const float4 g23 = *(const float4*)&PG[j * 18 + vb + 2];
        ar[0] = fmaf(g01.x, wr, fmaf(-g01.y, wi, ar[0]));
        ai[0] = fmaf(g01.x, wi, fmaf( g01.y, wr, ai[0]));
        ar[1] = fmaf(g01.z, wr, fmaf(-g01.w, wi, ar[1]));
        ai[1] = fmaf(g01.z, wi, fmaf( g01.w, wr, ai[1]));
        ar[2] = fmaf(g23.x, wr, fmaf(-g23.y, wi, ar[2]));
        ai[2] = fmaf(g23.x, wi, fmaf( g23.y, wr, ai[2]));
        ar[3] = fmaf(g23.z, wr, fmaf(-g23.w, wi, ar[3]));
        ai[3] = fmaf(g23.z, wi, fmaf( g23.w, wr, ai[3]));
        const float t  = wi * cii;
        const float nr = fmaf(wr, crr, -t);
        const float ni = fmaf(wr, cii, wi * crr);
        wr = nr; wi = ni;
    }

    float* outb = out + ((pair >> 2) << 12) + lane * 64 + vblk * 16 + vb;
    _Pragma("unroll")
    for (int c = 0; c < 4; ++c) {
        const float m = fmaf(ar[c], ar[c], ai[c] * ai[c]);
        atomicAdd(&outb[c], fmaf(m, scale, bgv));
    }
}

extern "C" void kernel_launch(void* const* d_in, const int* in_sizes, int n_in,
                              void* d_out, int out_size, void* d_ws, size_t ws_size,
                              hipStream_t stream)
{
    const float* x  = (const float*)d_in[0];
    const float* y  = (const float*)d_in[1];
    const float* z  = (const float*)d_in[2];
    const float* A  = (const float*)d_in[3];
    const float* bg = (const float*)d_in[4];
    const float* p  = (const float*)d_in[5];
    const float* ph = (const float*)d_in[6];
    float* out = (float*)d_out;

    float* maxws8 = (float*)d_ws;            // 2048 floats (8 partial maxes / pair)
    float* stash  = maxws8 + 2048;           // 256 x 4096 floats = 4 MB

    const size_t need_min = (2048u + 256u * 4096u) * sizeof(float);
    const int do_stash = (ws_size >= need_min) ? 1 : 0;

    hipLaunchKernelGGL(psf_max_kernel, dim3(2048), dim3(192), 0, stream,
                       x, y, z, p, ph, maxws8, stash, do_stash);
    if (do_stash) {
        hipLaunchKernelGGL(combine_kernel, dim3(256), dim3(256), 0, stream,
                           A, bg, p, maxws8, stash, out);
    } else {
        hipMemsetAsync(d_out, 0, (size_t)out_size * sizeof(float), stream);
        hipLaunchKernelGGL(psf_crop_kernel, dim3(1024), dim3(256), 0, stream,
                           x, y, z, A, bg, p, ph, maxws8, out);
    }
}